// Round 1
// baseline (364.063 us; speedup 1.0000x reference)
//
#include <hip/hip_runtime.h>
#include <math.h>

#define N_DET 2000
#define DET_STRIDE 84
#define TOPK 1000
#define CROP 14
#define C_CH 256

// ---------------------------------------------------------------------------
// K1: per-detection score (max over 80 classes) + FPN level
// ---------------------------------------------------------------------------
__global__ void k_score_level(const float* __restrict__ det,
                              float* __restrict__ scores,
                              int* __restrict__ levels) {
    int t = blockIdx.x * blockDim.x + threadIdx.x;
    if (t >= N_DET) return;
    const float* row = det + (size_t)t * DET_STRIDE;
    float s = row[4];
    for (int c = 5; c < DET_STRIDE; ++c) s = fmaxf(s, row[c]);
    scores[t] = s;
    float w = row[2] - row[0];
    float h = row[3] - row[1];
    float sz = sqrtf(w * h);
    float lv = floorf(1.0f + log2f(sz / 224.0f + 1e-7f));
    lv = fminf(fmaxf(lv, 0.0f), 4.0f);
    levels[t] = (int)lv;
}

// ---------------------------------------------------------------------------
// K2: exact top-k by rank counting (descending score, ties -> lower index)
// sel[rank] = detection index, for rank < TOPK
// ---------------------------------------------------------------------------
__global__ void k_rank(const float* __restrict__ scores,
                       int* __restrict__ sel) {
    __shared__ float s[N_DET];
    for (int i = threadIdx.x; i < N_DET; i += blockDim.x) s[i] = scores[i];
    __syncthreads();
    int t = blockIdx.x * blockDim.x + threadIdx.x;
    if (t >= N_DET) return;
    float mine = s[t];
    int rank = 0;
    for (int j = 0; j < N_DET; ++j) {
        float v = s[j];
        rank += (v > mine) || (v == mine && j < t);
    }
    if (rank < TOPK) sel[rank] = t;
}

// ---------------------------------------------------------------------------
// K3: stable sort of the 1000 selected by level (ascending), again by rank
// counting. meta[2*pos] = det index, meta[2*pos+1] = level.
// ---------------------------------------------------------------------------
__global__ void k_sort(const int* __restrict__ sel,
                       const int* __restrict__ levels,
                       int* __restrict__ meta) {
    __shared__ int lev[TOPK];
    __shared__ int idx[TOPK];
    int r = threadIdx.x;
    if (r < TOPK) {
        int di = sel[r];
        idx[r] = di;
        lev[r] = levels[di];
    }
    __syncthreads();
    if (r >= TOPK) return;
    int myl = lev[r];
    int pos = 0;
    for (int j = 0; j < TOPK; ++j) {
        int lj = lev[j];
        pos += (lj < myl) || (lj == myl && j < r);
    }
    meta[2 * pos] = idx[r];
    meta[2 * pos + 1] = myl;
}

// ---------------------------------------------------------------------------
// K4: det output copy (bit-exact gather)
// ---------------------------------------------------------------------------
__global__ void k_det(const float* __restrict__ det,
                      const int* __restrict__ meta,
                      float* __restrict__ out) {
    int e = blockIdx.x * blockDim.x + threadIdx.x;
    if (e >= TOPK * DET_STRIDE) return;
    int pos = e / DET_STRIDE;
    int col = e - pos * DET_STRIDE;
    out[e] = det[(size_t)meta[2 * pos] * DET_STRIDE + col];
}

// ---------------------------------------------------------------------------
// K5: crop_and_resize. One wave (64 lanes) per sample position (k,y,x);
// lane handles 4 channels via float4. 4 corner reads of 1KB each, 1KB write.
// ---------------------------------------------------------------------------
__global__ __launch_bounds__(256) void k_crop(
    const float* __restrict__ det, const int* __restrict__ meta,
    const int* __restrict__ ishape,
    const float* __restrict__ p3, const float* __restrict__ p4,
    const float* __restrict__ p5, const float* __restrict__ p6,
    const float* __restrict__ p7, float* __restrict__ rois) {
    int wid = threadIdx.x >> 6;
    int lane = threadIdx.x & 63;
    int p = blockIdx.x * 4 + wid;          // 0 .. 195999, wave-uniform
    int k = p / (CROP * CROP);
    int rem = p - k * (CROP * CROP);
    int yy = rem / CROP;
    int xx = rem - yy * CROP;

    int di = meta[2 * k];
    int level = meta[2 * k + 1];
    const float* drow = det + (size_t)di * DET_STRIDE;
    float imw = (float)ishape[2];
    float imh = (float)ishape[1];
    // boxes = (y1/h, x1/w, y2/h, x2/w); det cols are (x1,y1,x2,y2)
    float bx1 = drow[0] / imw;
    float by1 = drow[1] / imh;
    float bx2 = drow[2] / imw;
    float by2 = drow[3] / imh;

    int S;
    const float* fmap;
    switch (level) {
        case 0:  S = 100; fmap = p3; break;
        case 1:  S = 50;  fmap = p4; break;
        case 2:  S = 25;  fmap = p5; break;
        case 3:  S = 13;  fmap = p6; break;
        default: S = 7;   fmap = p7; break;
    }
    float Hs = (float)(S - 1);

    float ty = (float)yy / (float)(CROP - 1);
    float tx = (float)xx / (float)(CROP - 1);
    float iy = (by1 + ty * (by2 - by1)) * Hs;
    float ix = (bx1 + tx * (bx2 - bx1)) * Hs;
    float y0f = floorf(iy), x0f = floorf(ix);
    float ly = iy - y0f, lx = ix - x0f;
    int y0  = (int)fminf(fmaxf(y0f,        0.0f), Hs);
    int y1i = (int)fminf(fmaxf(y0f + 1.0f, 0.0f), Hs);
    int x0  = (int)fminf(fmaxf(x0f,        0.0f), Hs);
    int x1i = (int)fminf(fmaxf(x0f + 1.0f, 0.0f), Hs);
    bool valid = (iy >= 0.0f) & (iy <= Hs) & (ix >= 0.0f) & (ix <= Hs);

    const float4* tl = (const float4*)(fmap + ((size_t)y0  * S + x0 ) * C_CH);
    const float4* tr = (const float4*)(fmap + ((size_t)y0  * S + x1i) * C_CH);
    const float4* bl = (const float4*)(fmap + ((size_t)y1i * S + x0 ) * C_CH);
    const float4* br = (const float4*)(fmap + ((size_t)y1i * S + x1i) * C_CH);
    float4 a = tl[lane], b = tr[lane], c = bl[lane], d = br[lane];

    float4 o;
    {
        float tp = a.x + (b.x - a.x) * lx;
        float bt = c.x + (d.x - c.x) * lx;
        o.x = tp + (bt - tp) * ly;
    }
    {
        float tp = a.y + (b.y - a.y) * lx;
        float bt = c.y + (d.y - c.y) * lx;
        o.y = tp + (bt - tp) * ly;
    }
    {
        float tp = a.z + (b.z - a.z) * lx;
        float bt = c.z + (d.z - c.z) * lx;
        o.z = tp + (bt - tp) * ly;
    }
    {
        float tp = a.w + (b.w - a.w) * lx;
        float bt = c.w + (d.w - c.w) * lx;
        o.w = tp + (bt - tp) * ly;
    }
    if (!valid) o = make_float4(0.0f, 0.0f, 0.0f, 0.0f);

    float4* outp = (float4*)(rois + (size_t)p * C_CH);
    outp[lane] = o;
}

// ---------------------------------------------------------------------------
extern "C" void kernel_launch(void* const* d_in, const int* in_sizes, int n_in,
                              void* d_out, int out_size, void* d_ws, size_t ws_size,
                              hipStream_t stream) {
    const int* ishape  = (const int*)d_in[0];
    const float* det   = (const float*)d_in[1];
    const float* p3    = (const float*)d_in[2];
    const float* p4    = (const float*)d_in[3];
    const float* p5    = (const float*)d_in[4];
    const float* p6    = (const float*)d_in[5];
    const float* p7    = (const float*)d_in[6];
    float* out = (float*)d_out;

    float* scores = (float*)d_ws;                 // [2000]
    int*   levels = (int*)d_ws + N_DET;           // [2000]
    int*   sel    = (int*)d_ws + 2 * N_DET;       // [1000]
    int*   meta   = (int*)d_ws + 2 * N_DET + TOPK;// [2000]

    hipLaunchKernelGGL(k_score_level, dim3((N_DET + 255) / 256), dim3(256), 0, stream,
                       det, scores, levels);
    hipLaunchKernelGGL(k_rank, dim3((N_DET + 255) / 256), dim3(256), 0, stream,
                       scores, sel);
    hipLaunchKernelGGL(k_sort, dim3(1), dim3(1024), 0, stream,
                       sel, levels, meta);
    hipLaunchKernelGGL(k_det, dim3((TOPK * DET_STRIDE + 255) / 256), dim3(256), 0, stream,
                       det, meta, out);
    hipLaunchKernelGGL(k_crop, dim3(TOPK * CROP * CROP / 4), dim3(256), 0, stream,
                       det, meta, ishape, p3, p4, p5, p6, p7,
                       out + TOPK * DET_STRIDE);
}

// Round 3
// 259.591 us; speedup vs baseline: 1.4024x; 1.4024x over previous
//
#include <hip/hip_runtime.h>
#include <math.h>

#define N_DET 2000
#define DET_STRIDE 84
#define TOPK 1000
#define CROP 14
#define C_CH 256

// ---------------------------------------------------------------------------
// K1: one wave per detection. Lanes reduce the 80-class max via shfl;
// level computed with arithmetic identical to reference.
// ---------------------------------------------------------------------------
__global__ __launch_bounds__(256) void k_score_level(
    const float* __restrict__ det,
    float* __restrict__ scores, int* __restrict__ levels) {
    int w = blockIdx.x * 4 + (threadIdx.x >> 6);   // wave id = det index
    int lane = threadIdx.x & 63;
    if (w >= N_DET) return;
    const float* row = det + (size_t)w * DET_STRIDE;
    float s = row[4 + lane];                        // cols 4..67
    if (lane < 16) s = fmaxf(s, row[68 + lane]);    // cols 68..83
    #pragma unroll
    for (int m = 32; m >= 1; m >>= 1) s = fmaxf(s, __shfl_xor(s, m));
    if (lane == 0) {
        float bw = row[2] - row[0];
        float bh = row[3] - row[1];
        float sz = sqrtf(bw * bh);
        float lv = floorf(1.0f + log2f(sz / 224.0f + 1e-7f));
        lv = fminf(fmaxf(lv, 0.0f), 4.0f);
        scores[w] = s;
        levels[w] = (int)lv;
    }
}

// ---------------------------------------------------------------------------
// K2: exact top-k rank counting, one wave per detection; lanes split the
// 2000-element comparison loop, shfl-reduce the partial ranks.
// ---------------------------------------------------------------------------
__global__ __launch_bounds__(256) void k_rank(
    const float* __restrict__ scores, const int* __restrict__ levels,
    int* __restrict__ sel, int* __restrict__ levsel) {
    int t = blockIdx.x * 4 + (threadIdx.x >> 6);
    int lane = threadIdx.x & 63;
    if (t >= N_DET) return;
    float mine = scores[t];
    int cnt = 0;
    for (int j = lane; j < N_DET; j += 64) {
        float v = scores[j];
        cnt += (v > mine) || (v == mine && j < t);
    }
    #pragma unroll
    for (int m = 32; m >= 1; m >>= 1) cnt += __shfl_xor(cnt, m);
    if (lane == 0 && cnt < TOPK) {
        sel[cnt] = t;
        levsel[cnt] = levels[t];
    }
}

// ---------------------------------------------------------------------------
// K3: stable sort by level (rank counting, wave per element) + per-box
// precompute: normalized box float4, level, det index.
// ---------------------------------------------------------------------------
__global__ __launch_bounds__(256) void k_sort(
    const int* __restrict__ sel, const int* __restrict__ levsel,
    const float* __restrict__ det, const int* __restrict__ ishape,
    int* __restrict__ didx, int* __restrict__ lvl,
    float4* __restrict__ nbox) {
    int r = blockIdx.x * 4 + (threadIdx.x >> 6);
    int lane = threadIdx.x & 63;
    if (r >= TOPK) return;
    int myl = levsel[r];
    int pos = 0;
    for (int j = lane; j < TOPK; j += 64) {
        int lj = levsel[j];
        pos += (lj < myl) || (lj == myl && j < r);
    }
    #pragma unroll
    for (int m = 32; m >= 1; m >>= 1) pos += __shfl_xor(pos, m);
    if (lane == 0) {
        int di = sel[r];
        didx[pos] = di;
        lvl[pos] = myl;
        const float* drow = det + (size_t)di * DET_STRIDE;
        float imw = (float)ishape[2];
        float imh = (float)ishape[1];
        float4 nb;
        nb.x = drow[0] / imw;   // x1n
        nb.y = drow[1] / imh;   // y1n
        nb.z = drow[2] / imw;   // x2n
        nb.w = drow[3] / imh;   // y2n
        nbox[pos] = nb;
    }
}

// ---------------------------------------------------------------------------
// K4: det output copy (bit-exact gather)
// ---------------------------------------------------------------------------
__global__ void k_det(const float* __restrict__ det,
                      const int* __restrict__ didx,
                      float* __restrict__ out) {
    int e = blockIdx.x * blockDim.x + threadIdx.x;
    if (e >= TOPK * DET_STRIDE) return;
    int pos = e / DET_STRIDE;
    int col = e - pos * DET_STRIDE;
    out[e] = det[(size_t)didx[pos] * DET_STRIDE + col];
}

// ---------------------------------------------------------------------------
// K5: crop_and_resize. One wave per TWO consecutive sample positions
// (196 even -> a pair never straddles a box). Lane = 4 channels (float4).
// ---------------------------------------------------------------------------
__global__ __launch_bounds__(256) void k_crop(
    const float4* __restrict__ nbox, const int* __restrict__ lvl,
    const float* __restrict__ p3, const float* __restrict__ p4,
    const float* __restrict__ p5, const float* __restrict__ p6,
    const float* __restrict__ p7, float* __restrict__ rois) {
    int w = blockIdx.x * 4 + (threadIdx.x >> 6);
    int lane = threadIdx.x & 63;
    int p0 = w * 2;                       // even, pair (p0, p0+1) same box
    int k = p0 / (CROP * CROP);
    int rem = p0 - k * (CROP * CROP);
    int yyA = rem / CROP;
    int xxA = rem - yyA * CROP;
    int remB = rem + 1;
    int yyB = remB / CROP;
    int xxB = remB - yyB * CROP;

    float4 nb = nbox[k];
    int level = lvl[k];
    int S;
    const float* fmap;
    switch (level) {
        case 0:  S = 100; fmap = p3; break;
        case 1:  S = 50;  fmap = p4; break;
        case 2:  S = 25;  fmap = p5; break;
        case 3:  S = 13;  fmap = p6; break;
        default: S = 7;   fmap = p7; break;
    }
    float Hs = (float)(S - 1);

    // position A
    float tyA = (float)yyA / (float)(CROP - 1);
    float txA = (float)xxA / (float)(CROP - 1);
    float iyA = (nb.y + tyA * (nb.w - nb.y)) * Hs;
    float ixA = (nb.x + txA * (nb.z - nb.x)) * Hs;
    float y0fA = floorf(iyA), x0fA = floorf(ixA);
    float lyA = iyA - y0fA, lxA = ixA - x0fA;
    int y0A  = (int)fminf(fmaxf(y0fA,        0.0f), Hs);
    int y1A  = (int)fminf(fmaxf(y0fA + 1.0f, 0.0f), Hs);
    int x0A  = (int)fminf(fmaxf(x0fA,        0.0f), Hs);
    int x1A  = (int)fminf(fmaxf(x0fA + 1.0f, 0.0f), Hs);
    bool validA = (iyA >= 0.0f) & (iyA <= Hs) & (ixA >= 0.0f) & (ixA <= Hs);

    // position B
    float tyB = (float)yyB / (float)(CROP - 1);
    float txB = (float)xxB / (float)(CROP - 1);
    float iyB = (nb.y + tyB * (nb.w - nb.y)) * Hs;
    float ixB = (nb.x + txB * (nb.z - nb.x)) * Hs;
    float y0fB = floorf(iyB), x0fB = floorf(ixB);
    float lyB = iyB - y0fB, lxB = ixB - x0fB;
    int y0B  = (int)fminf(fmaxf(y0fB,        0.0f), Hs);
    int y1B  = (int)fminf(fmaxf(y0fB + 1.0f, 0.0f), Hs);
    int x0B  = (int)fminf(fmaxf(x0fB,        0.0f), Hs);
    int x1B  = (int)fminf(fmaxf(x0fB + 1.0f, 0.0f), Hs);
    bool validB = (iyB >= 0.0f) & (iyB <= Hs) & (ixB >= 0.0f) & (ixB <= Hs);

    const float4* tlA = (const float4*)(fmap + ((size_t)y0A * S + x0A) * C_CH);
    const float4* trA = (const float4*)(fmap + ((size_t)y0A * S + x1A) * C_CH);
    const float4* blA = (const float4*)(fmap + ((size_t)y1A * S + x0A) * C_CH);
    const float4* brA = (const float4*)(fmap + ((size_t)y1A * S + x1A) * C_CH);
    const float4* tlB = (const float4*)(fmap + ((size_t)y0B * S + x0B) * C_CH);
    const float4* trB = (const float4*)(fmap + ((size_t)y0B * S + x1B) * C_CH);
    const float4* blB = (const float4*)(fmap + ((size_t)y1B * S + x0B) * C_CH);
    const float4* brB = (const float4*)(fmap + ((size_t)y1B * S + x1B) * C_CH);

    float4 a0 = tlA[lane], a1 = trA[lane], a2 = blA[lane], a3 = brA[lane];
    float4 b0 = tlB[lane], b1 = trB[lane], b2 = blB[lane], b3 = brB[lane];

    float4 oA, oB;
    #define LERP1(f, a, b, c, d, lx, ly)                   \
        { float tp = a.f + (b.f - a.f) * lx;               \
          float bt = c.f + (d.f - c.f) * lx;               \
          float r_ = tp + (bt - tp) * ly;                  \
          outv.f = r_; }
    {
        float4 outv;
        LERP1(x, a0, a1, a2, a3, lxA, lyA)
        LERP1(y, a0, a1, a2, a3, lxA, lyA)
        LERP1(z, a0, a1, a2, a3, lxA, lyA)
        LERP1(w, a0, a1, a2, a3, lxA, lyA)
        oA = outv;
    }
    {
        float4 outv;
        LERP1(x, b0, b1, b2, b3, lxB, lyB)
        LERP1(y, b0, b1, b2, b3, lxB, lyB)
        LERP1(z, b0, b1, b2, b3, lxB, lyB)
        LERP1(w, b0, b1, b2, b3, lxB, lyB)
        oB = outv;
    }
    #undef LERP1
    if (!validA) oA = make_float4(0.0f, 0.0f, 0.0f, 0.0f);
    if (!validB) oB = make_float4(0.0f, 0.0f, 0.0f, 0.0f);

    float4* outA = (float4*)(rois + (size_t)p0 * C_CH);
    float4* outB = (float4*)(rois + (size_t)(p0 + 1) * C_CH);
    outA[lane] = oA;
    outB[lane] = oB;
}

// ---------------------------------------------------------------------------
extern "C" void kernel_launch(void* const* d_in, const int* in_sizes, int n_in,
                              void* d_out, int out_size, void* d_ws, size_t ws_size,
                              hipStream_t stream) {
    const int* ishape  = (const int*)d_in[0];
    const float* det   = (const float*)d_in[1];
    const float* p3    = (const float*)d_in[2];
    const float* p4    = (const float*)d_in[3];
    const float* p5    = (const float*)d_in[4];
    const float* p6    = (const float*)d_in[5];
    const float* p7    = (const float*)d_in[6];
    float* out = (float*)d_out;

    float4* nbox = (float4*)d_ws;                       // [1000] (16B aligned)
    float* fbase = (float*)d_ws + 4 * TOPK;
    float* scores = fbase;                              // [2000]
    int* levels = (int*)(fbase + N_DET);                // [2000]
    int* sel    = levels + N_DET;                       // [1000]
    int* levsel = sel + TOPK;                           // [1000]
    int* didx   = levsel + TOPK;                        // [1000]
    int* lvl    = didx + TOPK;                          // [1000]

    hipLaunchKernelGGL(k_score_level, dim3((N_DET + 3) / 4), dim3(256), 0, stream,
                       det, scores, levels);
    hipLaunchKernelGGL(k_rank, dim3((N_DET + 3) / 4), dim3(256), 0, stream,
                       scores, levels, sel, levsel);
    hipLaunchKernelGGL(k_sort, dim3((TOPK + 3) / 4), dim3(256), 0, stream,
                       sel, levsel, det, ishape, didx, lvl, nbox);
    hipLaunchKernelGGL(k_det, dim3((TOPK * DET_STRIDE + 255) / 256), dim3(256), 0, stream,
                       det, didx, out);
    hipLaunchKernelGGL(k_crop, dim3(TOPK * CROP * CROP / 8), dim3(256), 0, stream,
                       nbox, lvl, p3, p4, p5, p6, p7,
                       out + TOPK * DET_STRIDE);
}

// Round 11
// 258.599 us; speedup vs baseline: 1.4078x; 1.0038x over previous
//
#include <hip/hip_runtime.h>
#include <math.h>

#define N_DET 2000
#define DET_STRIDE 84
#define TOPK 1000
#define CROP 14
#define C_CH 256
#define CROP_BLOCKS (TOPK * CROP * CROP / 8)          // 24500: 4 waves/block, 2 pos/wave
#define DET_BLOCKS ((TOPK * DET_STRIDE + 255) / 256)  // 329

typedef float nfloat4 __attribute__((ext_vector_type(4)));  // native vec for nontemporal builtin

// ---------------------------------------------------------------------------
// K1: one wave per detection. Lanes reduce the 80-class max via shfl;
// level computed with arithmetic identical to reference.
// ---------------------------------------------------------------------------
__global__ __launch_bounds__(256) void k_score_level(
    const float* __restrict__ det,
    float* __restrict__ scores, int* __restrict__ levels) {
    int w = blockIdx.x * 4 + (threadIdx.x >> 6);   // wave id = det index
    int lane = threadIdx.x & 63;
    if (w >= N_DET) return;
    const float* row = det + (size_t)w * DET_STRIDE;
    float s = row[4 + lane];                        // cols 4..67
    if (lane < 16) s = fmaxf(s, row[68 + lane]);    // cols 68..83
    #pragma unroll
    for (int m = 32; m >= 1; m >>= 1) s = fmaxf(s, __shfl_xor(s, m));
    if (lane == 0) {
        float bw = row[2] - row[0];
        float bh = row[3] - row[1];
        float sz = sqrtf(bw * bh);
        float lv = floorf(1.0f + log2f(sz / 224.0f + 1e-7f));
        lv = fminf(fmaxf(lv, 0.0f), 4.0f);
        scores[w] = s;
        levels[w] = (int)lv;
    }
}

// ---------------------------------------------------------------------------
// K2: exact top-k rank counting, one wave per detection; lanes split the
// 2000-element comparison loop, shfl-reduce the partial ranks.
// ---------------------------------------------------------------------------
__global__ __launch_bounds__(256) void k_rank(
    const float* __restrict__ scores, const int* __restrict__ levels,
    int* __restrict__ sel, int* __restrict__ levsel) {
    int t = blockIdx.x * 4 + (threadIdx.x >> 6);
    int lane = threadIdx.x & 63;
    if (t >= N_DET) return;
    float mine = scores[t];
    int cnt = 0;
    for (int j = lane; j < N_DET; j += 64) {
        float v = scores[j];
        cnt += (v > mine) || (v == mine && j < t);
    }
    #pragma unroll
    for (int m = 32; m >= 1; m >>= 1) cnt += __shfl_xor(cnt, m);
    if (lane == 0 && cnt < TOPK) {
        sel[cnt] = t;
        levsel[cnt] = levels[t];
    }
}

// ---------------------------------------------------------------------------
// K3: stable sort by level (rank counting, wave per element) + per-box
// precompute: normalized box float4, level, det index.
// ---------------------------------------------------------------------------
__global__ __launch_bounds__(256) void k_sort(
    const int* __restrict__ sel, const int* __restrict__ levsel,
    const float* __restrict__ det, const int* __restrict__ ishape,
    int* __restrict__ didx, int* __restrict__ lvl,
    float4* __restrict__ nbox) {
    int r = blockIdx.x * 4 + (threadIdx.x >> 6);
    int lane = threadIdx.x & 63;
    if (r >= TOPK) return;
    int myl = levsel[r];
    int pos = 0;
    for (int j = lane; j < TOPK; j += 64) {
        int lj = levsel[j];
        pos += (lj < myl) || (lj == myl && j < r);
    }
    #pragma unroll
    for (int m = 32; m >= 1; m >>= 1) pos += __shfl_xor(pos, m);
    if (lane == 0) {
        int di = sel[r];
        didx[pos] = di;
        lvl[pos] = myl;
        const float* drow = det + (size_t)di * DET_STRIDE;
        float imw = (float)ishape[2];
        float imh = (float)ishape[1];
        float4 nb;
        nb.x = drow[0] / imw;   // x1n
        nb.y = drow[1] / imh;   // y1n
        nb.z = drow[2] / imw;   // x2n
        nb.w = drow[3] / imh;   // y2n
        nbox[pos] = nb;
    }
}

// ---------------------------------------------------------------------------
// K5: crop_and_resize + fused det copy.
// Blocks [0, CROP_BLOCKS): one wave per TWO consecutive sample positions
// (196 even -> a pair never straddles a box). Lane = 4 channels (float4).
// Output stores are NON-TEMPORAL: the 200 MB ROI stream must not evict
// the (L2-resident) feature map -> corner reads stay L2 hits.
// Blocks [CROP_BLOCKS, CROP_BLOCKS+DET_BLOCKS): bit-exact det gather-copy.
// ---------------------------------------------------------------------------
__global__ __launch_bounds__(256) void k_crop(
    const float4* __restrict__ nbox, const int* __restrict__ lvl,
    const int* __restrict__ didx, const float* __restrict__ det,
    const float* __restrict__ p3, const float* __restrict__ p4,
    const float* __restrict__ p5, const float* __restrict__ p6,
    const float* __restrict__ p7,
    float* __restrict__ detout, float* __restrict__ rois) {
    if (blockIdx.x >= CROP_BLOCKS) {
        int e = (blockIdx.x - CROP_BLOCKS) * 256 + threadIdx.x;
        if (e < TOPK * DET_STRIDE) {
            int pos = e / DET_STRIDE;
            int col = e - pos * DET_STRIDE;
            detout[e] = det[(size_t)didx[pos] * DET_STRIDE + col];
        }
        return;
    }
    int w = blockIdx.x * 4 + (threadIdx.x >> 6);
    int lane = threadIdx.x & 63;
    int p0 = w * 2;                       // even, pair (p0, p0+1) same box
    int k = p0 / (CROP * CROP);
    int rem = p0 - k * (CROP * CROP);
    int yyA = rem / CROP;
    int xxA = rem - yyA * CROP;
    int remB = rem + 1;
    int yyB = remB / CROP;
    int xxB = remB - yyB * CROP;

    float4 nb = nbox[k];
    int level = lvl[k];
    int S;
    const float* fmap;
    switch (level) {
        case 0:  S = 100; fmap = p3; break;
        case 1:  S = 50;  fmap = p4; break;
        case 2:  S = 25;  fmap = p5; break;
        case 3:  S = 13;  fmap = p6; break;
        default: S = 7;   fmap = p7; break;
    }
    float Hs = (float)(S - 1);

    // position A
    float tyA = (float)yyA / (float)(CROP - 1);
    float txA = (float)xxA / (float)(CROP - 1);
    float iyA = (nb.y + tyA * (nb.w - nb.y)) * Hs;
    float ixA = (nb.x + txA * (nb.z - nb.x)) * Hs;
    float y0fA = floorf(iyA), x0fA = floorf(ixA);
    float lyA = iyA - y0fA, lxA = ixA - x0fA;
    int y0A  = (int)fminf(fmaxf(y0fA,        0.0f), Hs);
    int y1A  = (int)fminf(fmaxf(y0fA + 1.0f, 0.0f), Hs);
    int x0A  = (int)fminf(fmaxf(x0fA,        0.0f), Hs);
    int x1A  = (int)fminf(fmaxf(x0fA + 1.0f, 0.0f), Hs);
    bool validA = (iyA >= 0.0f) & (iyA <= Hs) & (ixA >= 0.0f) & (ixA <= Hs);

    // position B
    float tyB = (float)yyB / (float)(CROP - 1);
    float txB = (float)xxB / (float)(CROP - 1);
    float iyB = (nb.y + tyB * (nb.w - nb.y)) * Hs;
    float ixB = (nb.x + txB * (nb.z - nb.x)) * Hs;
    float y0fB = floorf(iyB), x0fB = floorf(ixB);
    float lyB = iyB - y0fB, lxB = ixB - x0fB;
    int y0B  = (int)fminf(fmaxf(y0fB,        0.0f), Hs);
    int y1B  = (int)fminf(fmaxf(y0fB + 1.0f, 0.0f), Hs);
    int x0B  = (int)fminf(fmaxf(x0fB,        0.0f), Hs);
    int x1B  = (int)fminf(fmaxf(x0fB + 1.0f, 0.0f), Hs);
    bool validB = (iyB >= 0.0f) & (iyB <= Hs) & (ixB >= 0.0f) & (ixB <= Hs);

    const float4* tlA = (const float4*)(fmap + ((size_t)y0A * S + x0A) * C_CH);
    const float4* trA = (const float4*)(fmap + ((size_t)y0A * S + x1A) * C_CH);
    const float4* blA = (const float4*)(fmap + ((size_t)y1A * S + x0A) * C_CH);
    const float4* brA = (const float4*)(fmap + ((size_t)y1A * S + x1A) * C_CH);
    const float4* tlB = (const float4*)(fmap + ((size_t)y0B * S + x0B) * C_CH);
    const float4* trB = (const float4*)(fmap + ((size_t)y0B * S + x1B) * C_CH);
    const float4* blB = (const float4*)(fmap + ((size_t)y1B * S + x0B) * C_CH);
    const float4* brB = (const float4*)(fmap + ((size_t)y1B * S + x1B) * C_CH);

    float4 a0 = tlA[lane], a1 = trA[lane], a2 = blA[lane], a3 = brA[lane];
    float4 b0 = tlB[lane], b1 = trB[lane], b2 = blB[lane], b3 = brB[lane];

    float4 oA, oB;
    #define LERP1(f, a, b, c, d, lx, ly)                   \
        { float tp = a.f + (b.f - a.f) * lx;               \
          float bt = c.f + (d.f - c.f) * lx;               \
          float r_ = tp + (bt - tp) * ly;                  \
          outv.f = r_; }
    {
        float4 outv;
        LERP1(x, a0, a1, a2, a3, lxA, lyA)
        LERP1(y, a0, a1, a2, a3, lxA, lyA)
        LERP1(z, a0, a1, a2, a3, lxA, lyA)
        LERP1(w, a0, a1, a2, a3, lxA, lyA)
        oA = outv;
    }
    {
        float4 outv;
        LERP1(x, b0, b1, b2, b3, lxB, lyB)
        LERP1(y, b0, b1, b2, b3, lxB, lyB)
        LERP1(z, b0, b1, b2, b3, lxB, lyB)
        LERP1(w, b0, b1, b2, b3, lxB, lyB)
        oB = outv;
    }
    #undef LERP1
    if (!validA) oA = make_float4(0.0f, 0.0f, 0.0f, 0.0f);
    if (!validB) oB = make_float4(0.0f, 0.0f, 0.0f, 0.0f);

    nfloat4 nA = { oA.x, oA.y, oA.z, oA.w };
    nfloat4 nB = { oB.x, oB.y, oB.z, oB.w };
    nfloat4* outA = (nfloat4*)(rois + (size_t)p0 * C_CH) + lane;
    nfloat4* outB = (nfloat4*)(rois + (size_t)(p0 + 1) * C_CH) + lane;
    __builtin_nontemporal_store(nA, outA);
    __builtin_nontemporal_store(nB, outB);
}

// ---------------------------------------------------------------------------
extern "C" void kernel_launch(void* const* d_in, const int* in_sizes, int n_in,
                              void* d_out, int out_size, void* d_ws, size_t ws_size,
                              hipStream_t stream) {
    const int* ishape  = (const int*)d_in[0];
    const float* det   = (const float*)d_in[1];
    const float* p3    = (const float*)d_in[2];
    const float* p4    = (const float*)d_in[3];
    const float* p5    = (const float*)d_in[4];
    const float* p6    = (const float*)d_in[5];
    const float* p7    = (const float*)d_in[6];
    float* out = (float*)d_out;

    float4* nbox = (float4*)d_ws;                       // [1000] (16B aligned)
    float* fbase = (float*)d_ws + 4 * TOPK;
    float* scores = fbase;                              // [2000]
    int* levels = (int*)(fbase + N_DET);                // [2000]
    int* sel    = levels + N_DET;                       // [1000]
    int* levsel = sel + TOPK;                           // [1000]
    int* didx   = levsel + TOPK;                        // [1000]
    int* lvl    = didx + TOPK;                          // [1000]

    hipLaunchKernelGGL(k_score_level, dim3((N_DET + 3) / 4), dim3(256), 0, stream,
                       det, scores, levels);
    hipLaunchKernelGGL(k_rank, dim3((N_DET + 3) / 4), dim3(256), 0, stream,
                       scores, levels, sel, levsel);
    hipLaunchKernelGGL(k_sort, dim3((TOPK + 3) / 4), dim3(256), 0, stream,
                       sel, levsel, det, ishape, didx, lvl, nbox);
    hipLaunchKernelGGL(k_crop, dim3(CROP_BLOCKS + DET_BLOCKS), dim3(256), 0, stream,
                       nbox, lvl, didx, det, p3, p4, p5, p6, p7,
                       out, out + TOPK * DET_STRIDE);
}

// Round 13
// 251.690 us; speedup vs baseline: 1.4465x; 1.0275x over previous
//
#include <hip/hip_runtime.h>
#include <math.h>

#define N_DET 2000
#define DET_STRIDE 84
#define TOPK 1000
#define CROP 14
#define C_CH 256
#define POS_PER_BOX (CROP * CROP)                     // 196
#define POS_PER_WAVE 4
#define POS_PER_BLOCK 16                              // 4 waves x 4 positions
#define BLOCKS_PER_BOX 13                             // ceil(196/16), last 12 slots masked
#define CROP_BLOCKS (TOPK * BLOCKS_PER_BOX)           // 13000 = 8 XCDs x 1625
#define DET_BLOCKS ((TOPK * DET_STRIDE + 255) / 256)  // 329

typedef float nfloat4 __attribute__((ext_vector_type(4)));  // native vec for nontemporal builtin

// ---------------------------------------------------------------------------
// K1: one wave per detection. Lanes reduce the 80-class max via shfl;
// level computed with arithmetic identical to reference.
// ---------------------------------------------------------------------------
__global__ __launch_bounds__(256) void k_score_level(
    const float* __restrict__ det,
    float* __restrict__ scores, int* __restrict__ levels) {
    int w = blockIdx.x * 4 + (threadIdx.x >> 6);   // wave id = det index
    int lane = threadIdx.x & 63;
    if (w >= N_DET) return;
    const float* row = det + (size_t)w * DET_STRIDE;
    float s = row[4 + lane];                        // cols 4..67
    if (lane < 16) s = fmaxf(s, row[68 + lane]);    // cols 68..83
    #pragma unroll
    for (int m = 32; m >= 1; m >>= 1) s = fmaxf(s, __shfl_xor(s, m));
    if (lane == 0) {
        float bw = row[2] - row[0];
        float bh = row[3] - row[1];
        float sz = sqrtf(bw * bh);
        float lv = floorf(1.0f + log2f(sz / 224.0f + 1e-7f));
        lv = fminf(fmaxf(lv, 0.0f), 4.0f);
        scores[w] = s;
        levels[w] = (int)lv;
    }
}

// ---------------------------------------------------------------------------
// K2: exact top-k rank counting, one wave per detection; lanes split the
// 2000-element comparison loop, shfl-reduce the partial ranks.
// ---------------------------------------------------------------------------
__global__ __launch_bounds__(256) void k_rank(
    const float* __restrict__ scores, const int* __restrict__ levels,
    int* __restrict__ sel, int* __restrict__ levsel) {
    int t = blockIdx.x * 4 + (threadIdx.x >> 6);
    int lane = threadIdx.x & 63;
    if (t >= N_DET) return;
    float mine = scores[t];
    int cnt = 0;
    for (int j = lane; j < N_DET; j += 64) {
        float v = scores[j];
        cnt += (v > mine) || (v == mine && j < t);
    }
    #pragma unroll
    for (int m = 32; m >= 1; m >>= 1) cnt += __shfl_xor(cnt, m);
    if (lane == 0 && cnt < TOPK) {
        sel[cnt] = t;
        levsel[cnt] = levels[t];
    }
}

// ---------------------------------------------------------------------------
// K3: stable sort by level (rank counting, wave per element) + per-box
// precompute: normalized box float4, level, det index.
// ---------------------------------------------------------------------------
__global__ __launch_bounds__(256) void k_sort(
    const int* __restrict__ sel, const int* __restrict__ levsel,
    const float* __restrict__ det, const int* __restrict__ ishape,
    int* __restrict__ didx, int* __restrict__ lvl,
    float4* __restrict__ nbox) {
    int r = blockIdx.x * 4 + (threadIdx.x >> 6);
    int lane = threadIdx.x & 63;
    if (r >= TOPK) return;
    int myl = levsel[r];
    int pos = 0;
    for (int j = lane; j < TOPK; j += 64) {
        int lj = levsel[j];
        pos += (lj < myl) || (lj == myl && j < r);
    }
    #pragma unroll
    for (int m = 32; m >= 1; m >>= 1) pos += __shfl_xor(pos, m);
    if (lane == 0) {
        int di = sel[r];
        didx[pos] = di;
        lvl[pos] = myl;
        const float* drow = det + (size_t)di * DET_STRIDE;
        float imw = (float)ishape[2];
        float imh = (float)ishape[1];
        float4 nb;
        nb.x = drow[0] / imw;   // x1n
        nb.y = drow[1] / imh;   // y1n
        nb.z = drow[2] / imw;   // x2n
        nb.w = drow[3] / imh;   // y2n
        nbox[pos] = nb;
    }
}

// ---------------------------------------------------------------------------
// K5: crop_and_resize + fused det copy.
// Geometry: 13 blocks per box, 4 waves x 4 positions each (last 12 of 208
// slots masked). Block->box mapping is XCD-COHERENT: all 13 blocks of a box
// land on the same XCD (hw round-robins blockIdx%8), so the box's feature
// cells live in ONE L2 instead of being duplicated across 8 -> corner reads
// become L2 hits. 16 independent corner loads in flight per wave (4 pos).
// Blocks [CROP_BLOCKS, CROP_BLOCKS+DET_BLOCKS): bit-exact det gather-copy.
// ---------------------------------------------------------------------------
__global__ __launch_bounds__(256) void k_crop(
    const float4* __restrict__ nbox, const int* __restrict__ lvl,
    const int* __restrict__ didx, const float* __restrict__ det,
    const float* __restrict__ p3, const float* __restrict__ p4,
    const float* __restrict__ p5, const float* __restrict__ p6,
    const float* __restrict__ p7,
    float* __restrict__ detout, float* __restrict__ rois) {
    if (blockIdx.x >= CROP_BLOCKS) {
        int e = (blockIdx.x - CROP_BLOCKS) * 256 + threadIdx.x;
        if (e < TOPK * DET_STRIDE) {
            int pos = e / DET_STRIDE;
            int col = e - pos * DET_STRIDE;
            detout[e] = det[(size_t)didx[pos] * DET_STRIDE + col];
        }
        return;
    }
    int wv = threadIdx.x >> 6;
    int lane = threadIdx.x & 63;
    int b = blockIdx.x;
    int xcd = b & 7;                       // dispatch round-robins XCDs
    int t = b >> 3;                        // 0..1624
    int grp = t / BLOCKS_PER_BOX;          // 0..124
    int ib = t - grp * BLOCKS_PER_BOX;     // block-within-box 0..12
    int k = grp * 8 + xcd;                 // box 0..999 (bijective)
    int local0 = ib * POS_PER_BLOCK + wv * POS_PER_WAVE;

    float4 nb = nbox[k];
    int level = lvl[k];
    int S;
    const float* fmap;
    switch (level) {
        case 0:  S = 100; fmap = p3; break;
        case 1:  S = 50;  fmap = p4; break;
        case 2:  S = 25;  fmap = p5; break;
        case 3:  S = 13;  fmap = p6; break;
        default: S = 7;   fmap = p7; break;
    }
    float Hs = (float)(S - 1);

    // phase 1: coordinates + addresses for 4 positions (static unroll)
    const float4* ptl[POS_PER_WAVE];
    const float4* ptr_[POS_PER_WAVE];
    const float4* pbl[POS_PER_WAVE];
    const float4* pbr[POS_PER_WAVE];
    float plx[POS_PER_WAVE], ply[POS_PER_WAVE];
    bool plive[POS_PER_WAVE];
    #pragma unroll
    for (int j = 0; j < POS_PER_WAVE; ++j) {
        int local = local0 + j;
        bool live = local < POS_PER_BOX;
        int lc = live ? local : 0;
        int yy = lc / CROP;
        int xx = lc - yy * CROP;
        float ty = (float)yy / (float)(CROP - 1);
        float tx = (float)xx / (float)(CROP - 1);
        float iy = (nb.y + ty * (nb.w - nb.y)) * Hs;
        float ix = (nb.x + tx * (nb.z - nb.x)) * Hs;
        float y0f = floorf(iy), x0f = floorf(ix);
        float ly = iy - y0f, lx = ix - x0f;
        int y0  = (int)fminf(fmaxf(y0f,        0.0f), Hs);
        int y1  = (int)fminf(fmaxf(y0f + 1.0f, 0.0f), Hs);
        int x0  = (int)fminf(fmaxf(x0f,        0.0f), Hs);
        int x1  = (int)fminf(fmaxf(x0f + 1.0f, 0.0f), Hs);
        bool valid = (iy >= 0.0f) & (iy <= Hs) & (ix >= 0.0f) & (ix <= Hs);
        ptl[j]  = (const float4*)(fmap + ((size_t)y0 * S + x0) * C_CH);
        ptr_[j] = (const float4*)(fmap + ((size_t)y0 * S + x1) * C_CH);
        pbl[j]  = (const float4*)(fmap + ((size_t)y1 * S + x0) * C_CH);
        pbr[j]  = (const float4*)(fmap + ((size_t)y1 * S + x1) * C_CH);
        plx[j] = lx;
        ply[j] = ly;
        plive[j] = live && valid;
    }

    // phase 2: issue all 16 corner loads (independent -> deep MLP)
    float4 ctl[POS_PER_WAVE], ctr[POS_PER_WAVE], cbl[POS_PER_WAVE], cbr[POS_PER_WAVE];
    #pragma unroll
    for (int j = 0; j < POS_PER_WAVE; ++j) {
        ctl[j] = ptl[j][lane];
        ctr[j] = ptr_[j][lane];
        cbl[j] = pbl[j][lane];
        cbr[j] = pbr[j][lane];
    }

    // phase 3: lerp + nontemporal store
    #pragma unroll
    for (int j = 0; j < POS_PER_WAVE; ++j) {
        float lx = plx[j], ly = ply[j];
        float4 o;
        {
            float tp = ctl[j].x + (ctr[j].x - ctl[j].x) * lx;
            float bt = cbl[j].x + (cbr[j].x - cbl[j].x) * lx;
            o.x = tp + (bt - tp) * ly;
        }
        {
            float tp = ctl[j].y + (ctr[j].y - ctl[j].y) * lx;
            float bt = cbl[j].y + (cbr[j].y - cbl[j].y) * lx;
            o.y = tp + (bt - tp) * ly;
        }
        {
            float tp = ctl[j].z + (ctr[j].z - ctl[j].z) * lx;
            float bt = cbl[j].z + (cbr[j].z - cbl[j].z) * lx;
            o.z = tp + (bt - tp) * ly;
        }
        {
            float tp = ctl[j].w + (ctr[j].w - ctl[j].w) * lx;
            float bt = cbl[j].w + (cbr[j].w - cbl[j].w) * lx;
            o.w = tp + (bt - tp) * ly;
        }
        int local = local0 + j;
        if (local < POS_PER_BOX) {
            if (!plive[j]) o = make_float4(0.0f, 0.0f, 0.0f, 0.0f);
            nfloat4 nv = { o.x, o.y, o.z, o.w };
            nfloat4* outp = (nfloat4*)(rois + ((size_t)k * POS_PER_BOX + local) * C_CH) + lane;
            __builtin_nontemporal_store(nv, outp);
        }
    }
}

// ---------------------------------------------------------------------------
extern "C" void kernel_launch(void* const* d_in, const int* in_sizes, int n_in,
                              void* d_out, int out_size, void* d_ws, size_t ws_size,
                              hipStream_t stream) {
    const int* ishape  = (const int*)d_in[0];
    const float* det   = (const float*)d_in[1];
    const float* p3    = (const float*)d_in[2];
    const float* p4    = (const float*)d_in[3];
    const float* p5    = (const float*)d_in[4];
    const float* p6    = (const float*)d_in[5];
    const float* p7    = (const float*)d_in[6];
    float* out = (float*)d_out;

    float4* nbox = (float4*)d_ws;                       // [1000] (16B aligned)
    float* fbase = (float*)d_ws + 4 * TOPK;
    float* scores = fbase;                              // [2000]
    int* levels = (int*)(fbase + N_DET);                // [2000]
    int* sel    = levels + N_DET;                       // [1000]
    int* levsel = sel + TOPK;                           // [1000]
    int* didx   = levsel + TOPK;                        // [1000]
    int* lvl    = didx + TOPK;                          // [1000]

    hipLaunchKernelGGL(k_score_level, dim3((N_DET + 3) / 4), dim3(256), 0, stream,
                       det, scores, levels);
    hipLaunchKernelGGL(k_rank, dim3((N_DET + 3) / 4), dim3(256), 0, stream,
                       scores, levels, sel, levsel);
    hipLaunchKernelGGL(k_sort, dim3((TOPK + 3) / 4), dim3(256), 0, stream,
                       sel, levsel, det, ishape, didx, lvl, nbox);
    hipLaunchKernelGGL(k_crop, dim3(CROP_BLOCKS + DET_BLOCKS), dim3(256), 0, stream,
                       nbox, lvl, didx, det, p3, p4, p5, p6, p7,
                       out, out + TOPK * DET_STRIDE);
}